// Round 1
// baseline (96.693 us; speedup 1.0000x reference)
//
#include <hip/hip_runtime.h>

static constexpr int B_ = 64;
static constexpr int L_ = 1 << 20;
static constexpr int OUT_LEN = 2 * (L_ >> 2) - 1; // 524287

__device__ __forceinline__ float dot4(const float4& v, float t0, float t1, float t2, float t3) {
    return fmaf(v.x, t0, fmaf(v.y, t1, fmaf(v.z, t2, v.w * t3)));
}

__global__ __launch_bounds__(256) void multiscale_conv(
    const float* __restrict__ data,
    const float* __restrict__ weights,
    const float* __restrict__ bias,
    float* __restrict__ out)
{
    const int lane = threadIdx.x & 63;
    const int wave = threadIdx.x >> 6;
    const int g = blockIdx.x * 4 + wave;   // global 1024-elem chunk id
    const int b = g >> 10;                 // row (1024 chunks per row)
    const int c = g & 1023;                // chunk within row

    const float4* dp = reinterpret_cast<const float4*>(data + (size_t)b * L_ + (size_t)c * 1024);
    const float4 v0 = dp[lane];
    const float4 v1 = dp[lane + 64];
    const float4 v2 = dp[lane + 128];
    const float4 v3 = dp[lane + 192];

    float* orow = out + (size_t)b * OUT_LEN;

    // out[:, 0:1023) must be zero (harness poisons d_out with 0xAA)
    if (c == 0) {
        for (int j = lane; j < 1023; j += 64) orow[j] = 0.0f;
    }

    // scales s=2..8 (w = 4..256): each segment lives inside a 256-elem sub-block
#pragma unroll
    for (int s = 2; s <= 8; ++s) {
        const int w = 1 << s;
        const int m = w >> 2;  // lanes per segment (1..64)
        const float* tp = weights + (w - 1) + ((lane & (m - 1)) << 2);
        const float t0 = tp[0], t1 = tp[1], t2 = tp[2], t3 = tp[3];
        float p0 = dot4(v0, t0, t1, t2, t3);
        float p1 = dot4(v1, t0, t1, t2, t3);
        float p2 = dot4(v2, t0, t1, t2, t3);
        float p3 = dot4(v3, t0, t1, t2, t3);
#pragma unroll
        for (int d = 1; d < m; d <<= 1) {
            p0 += __shfl_xor(p0, d);
            p1 += __shfl_xor(p1, d);
            p2 += __shfl_xor(p2, d);
            p3 += __shfl_xor(p3, d);
        }
        if ((lane & (m - 1)) == 0) {
            const int base = (L_ >> s) - 1;       // region start k-1
            const int sps  = 256 >> s;            // segments per sub-block
            const int seg  = c * (1024 >> s) + (lane >> (s - 2));
            const float bs = bias[s - 1];
            orow[base + seg          ] = p0 + bs;
            orow[base + seg +     sps] = p1 + bs;
            orow[base + seg + 2 * sps] = p2 + bs;
            orow[base + seg + 3 * sps] = p3 + bs;
        }
    }

    // s = 9 (w = 512): two segments per chunk, full-wave reduction
    {
        const float* ta = weights + 511 + (lane << 2);
        const float* tb = ta + 256;
        const float a0 = ta[0], a1 = ta[1], a2 = ta[2], a3 = ta[3];
        const float b0 = tb[0], b1 = tb[1], b2 = tb[2], b3 = tb[3];
        float p = dot4(v0, a0, a1, a2, a3) + dot4(v1, b0, b1, b2, b3);
        float q = dot4(v2, a0, a1, a2, a3) + dot4(v3, b0, b1, b2, b3);
#pragma unroll
        for (int d = 1; d < 64; d <<= 1) {
            p += __shfl_xor(p, d);
            q += __shfl_xor(q, d);
        }
        if (lane < 2) {
            orow[((L_ >> 9) - 1) + 2 * c + lane] = (lane == 0 ? p : q) + bias[8];
        }
    }

    // s = 10 (w = 1024): one segment per chunk
    {
        const float* t = weights + 1023 + (lane << 2);
        float p = dot4(v0, t[0],   t[1],   t[2],   t[3]);
        p      += dot4(v1, t[256], t[257], t[258], t[259]);
        p      += dot4(v2, t[512], t[513], t[514], t[515]);
        p      += dot4(v3, t[768], t[769], t[770], t[771]);
#pragma unroll
        for (int d = 1; d < 64; d <<= 1) p += __shfl_xor(p, d);
        if (lane == 0) orow[((L_ >> 10) - 1) + c] = p + bias[9];
    }
}

extern "C" void kernel_launch(void* const* d_in, const int* in_sizes, int n_in,
                              void* d_out, int out_size, void* d_ws, size_t ws_size,
                              hipStream_t stream) {
    const float* data    = (const float*)d_in[0];
    const float* weights = (const float*)d_in[1];
    const float* bias    = (const float*)d_in[2];
    float* out = (float*)d_out;

    const int n_chunks = B_ * (L_ / 1024);      // 65536 waves
    dim3 grid(n_chunks / 4);                    // 4 waves (256 thr) per block
    dim3 block(256);
    multiscale_conv<<<grid, block, 0, stream>>>(data, weights, bias, out);
}

// Round 2
// 87.278 us; speedup vs baseline: 1.1079x; 1.1079x over previous
//
#include <hip/hip_runtime.h>

static constexpr int B_ = 64;
static constexpr int L_ = 1 << 20;
static constexpr int OUT_LEN = 2 * (L_ >> 2) - 1; // 524287

__device__ __forceinline__ float dot4(const float4& v, float t0, float t1, float t2, float t3) {
    return fmaf(v.x, t0, fmaf(v.y, t1, fmaf(v.z, t2, v.w * t3)));
}

// v += dpp(v) on the VALU pipe. old=0 so masked-off rows contribute +0.
template<int CTRL, int RM>
__device__ __forceinline__ float dpp_add(float v) {
    int t = __builtin_amdgcn_update_dpp(0, __builtin_bit_cast(int, v), CTRL, RM, 0xF, true);
    return v + __builtin_bit_cast(float, t);
}

// Segmented sum over groups of M consecutive lanes (M power of 2, divides 64).
// Result valid in the LAST lane of each group (lane % M == M-1); other lanes
// hold cross-window garbage that is never read. Pure VALU (DPP), no DS pipe.
template<int M>
__device__ __forceinline__ float seg_reduce(float v) {
    if constexpr (M >= 2)  v = dpp_add<0x111, 0xF>(v);  // row_shr:1
    if constexpr (M >= 4)  v = dpp_add<0x112, 0xF>(v);  // row_shr:2
    if constexpr (M >= 8)  v = dpp_add<0x114, 0xF>(v);  // row_shr:4
    if constexpr (M >= 16) v = dpp_add<0x118, 0xF>(v);  // row_shr:8
    if constexpr (M >= 32) v = dpp_add<0x142, 0xA>(v);  // row_bcast15 -> rows 1,3
    if constexpr (M >= 64) v = dpp_add<0x143, 0xC>(v);  // row_bcast31 -> rows 2,3
    return v;
}

template<int S>
__device__ __forceinline__ void do_scale(const float4& v0, const float4& v1,
                                         const float4& v2, const float4& v3,
                                         const float* __restrict__ weights,
                                         const float* __restrict__ bias,
                                         float* __restrict__ orow, int c, int lane) {
    constexpr int w = 1 << S;
    constexpr int m = w >> 2;            // lanes per segment
    const float* tp = weights + (w - 1) + ((lane & (m - 1)) << 2);
    const float t0 = tp[0], t1 = tp[1], t2 = tp[2], t3 = tp[3];
    float p0 = dot4(v0, t0, t1, t2, t3);
    float p1 = dot4(v1, t0, t1, t2, t3);
    float p2 = dot4(v2, t0, t1, t2, t3);
    float p3 = dot4(v3, t0, t1, t2, t3);
    p0 = seg_reduce<m>(p0);
    p1 = seg_reduce<m>(p1);
    p2 = seg_reduce<m>(p2);
    p3 = seg_reduce<m>(p3);
    if ((lane & (m - 1)) == (m - 1)) {
        constexpr int base = (L_ >> S) - 1;  // region start k-1
        constexpr int sps  = 256 >> S;       // segments per 256-elem sub-block
        const int seg = c * (1024 >> S) + (lane >> (S - 2));
        const float bs = bias[S - 1];
        orow[base + seg          ] = p0 + bs;
        orow[base + seg +     sps] = p1 + bs;
        orow[base + seg + 2 * sps] = p2 + bs;
        orow[base + seg + 3 * sps] = p3 + bs;
    }
}

__global__ __launch_bounds__(256) void multiscale_conv(
    const float* __restrict__ data,
    const float* __restrict__ weights,
    const float* __restrict__ bias,
    float* __restrict__ out)
{
    const int lane = threadIdx.x & 63;
    const int wave = threadIdx.x >> 6;
    const int g = blockIdx.x * 4 + wave;   // global 1024-elem chunk id
    const int b = g >> 10;                 // row (1024 chunks per row)
    const int c = g & 1023;                // chunk within row

    const float4* dp = reinterpret_cast<const float4*>(data + (size_t)b * L_ + (size_t)c * 1024);
    const float4 v0 = dp[lane];
    const float4 v1 = dp[lane + 64];
    const float4 v2 = dp[lane + 128];
    const float4 v3 = dp[lane + 192];

    float* orow = out + (size_t)b * OUT_LEN;

    // out[:, 0:1023) must be zero (harness poisons d_out with 0xAA)
    if (c == 0) {
        for (int j = lane; j < 1023; j += 64) orow[j] = 0.0f;
    }

    // scales s=2..8: segments live inside a 256-elem sub-block
    do_scale<2>(v0, v1, v2, v3, weights, bias, orow, c, lane);
    do_scale<3>(v0, v1, v2, v3, weights, bias, orow, c, lane);
    do_scale<4>(v0, v1, v2, v3, weights, bias, orow, c, lane);
    do_scale<5>(v0, v1, v2, v3, weights, bias, orow, c, lane);
    do_scale<6>(v0, v1, v2, v3, weights, bias, orow, c, lane);
    do_scale<7>(v0, v1, v2, v3, weights, bias, orow, c, lane);
    do_scale<8>(v0, v1, v2, v3, weights, bias, orow, c, lane);

    // s = 9 (w = 512): two segments per chunk, full-wave reduction
    {
        const float* ta = weights + 511 + (lane << 2);
        const float* tb = ta + 256;
        const float a0 = ta[0], a1 = ta[1], a2 = ta[2], a3 = ta[3];
        const float b0 = tb[0], b1 = tb[1], b2 = tb[2], b3 = tb[3];
        float p = dot4(v0, a0, a1, a2, a3) + dot4(v1, b0, b1, b2, b3);
        float q = dot4(v2, a0, a1, a2, a3) + dot4(v3, b0, b1, b2, b3);
        p = seg_reduce<64>(p);
        q = seg_reduce<64>(q);
        if (lane == 63) {
            const float bs = bias[8];
            orow[((L_ >> 9) - 1) + 2 * c    ] = p + bs;
            orow[((L_ >> 9) - 1) + 2 * c + 1] = q + bs;
        }
    }

    // s = 10 (w = 1024): one segment per chunk
    {
        const float* t = weights + 1023 + (lane << 2);
        float p = dot4(v0, t[0],   t[1],   t[2],   t[3]);
        p      += dot4(v1, t[256], t[257], t[258], t[259]);
        p      += dot4(v2, t[512], t[513], t[514], t[515]);
        p      += dot4(v3, t[768], t[769], t[770], t[771]);
        p = seg_reduce<64>(p);
        if (lane == 63) orow[((L_ >> 10) - 1) + c] = p + bias[9];
    }
}

extern "C" void kernel_launch(void* const* d_in, const int* in_sizes, int n_in,
                              void* d_out, int out_size, void* d_ws, size_t ws_size,
                              hipStream_t stream) {
    const float* data    = (const float*)d_in[0];
    const float* weights = (const float*)d_in[1];
    const float* bias    = (const float*)d_in[2];
    float* out = (float*)d_out;

    const int n_chunks = B_ * (L_ / 1024);      // 65536 waves
    dim3 grid(n_chunks / 4);                    // 4 waves (256 thr) per block
    dim3 block(256);
    multiscale_conv<<<grid, block, 0, stream>>>(data, weights, bias, out);
}